// Round 1
// baseline (545.535 us; speedup 1.0000x reference)
//
#include <hip/hip_runtime.h>
#include <hip/hip_bf16.h>
#include <math.h>
#include <float.h>

#define TPB 256

// One block per image. Fully fused: conv1 -> relu -> conv2 -> relu -> maxpool3
// -> fc -> softmax -> 9-step conv scan -> prob-weighted mix. All intermediates
// live in LDS (zero-padded 32x32 layouts => branch-free 5x5 taps).
__launch_bounds__(TPB, 2)
__global__ void modeld_fused(const float* __restrict__ xg,
                             const float* __restrict__ w1g,
                             const float* __restrict__ b1g,
                             const float* __restrict__ w2g,
                             const float* __restrict__ b2g,
                             const float* __restrict__ fcwg,
                             const float* __restrict__ fcbg,
                             const float* __restrict__ iwg,
                             float* __restrict__ outg)
{
    __shared__ float spad[1024];      // padded 32x32 input image (borders 0)
    __shared__ float sh1[8 * 1032];   // conv1 out, 8 channels, padded 32x32, stride 1032 (bank stagger)
    __shared__ float pooled[1296];    // [c*81 + s], c<16, s=py*9+px
    __shared__ float sw1[200];        // w1 natural layout [c][25]
    __shared__ float sb1[8];
    __shared__ float sw2t[3200];      // w2 transposed: [(ic*25+k)*16 + c]
    __shared__ float sb2[16];
    __shared__ float siterw[32];
    __shared__ float sprobs[16];
    __shared__ float swred[64];       // 4 waves x 10 partial logits
    __shared__ float acc[784];

    const int tid = threadIdx.x;
    const int b = blockIdx.x;

    // ---- phase 0: zero padded buffers, stage weights ----
    for (int i = tid; i < 1024; i += TPB) spad[i] = 0.f;
    for (int i = tid; i < 8 * 1032; i += TPB) sh1[i] = 0.f;
    for (int i = tid; i < 200; i += TPB) sw1[i] = w1g[i];
    if (tid < 8)  sb1[tid] = b1g[tid];
    for (int o = tid; o < 3200; o += TPB) {
        int c = o & 15, r = o >> 4;            // r = ic*25 + k
        sw2t[o] = w2g[c * 200 + r];
    }
    if (tid < 16) sb2[tid] = b2g[tid];
    if (tid < 25) siterw[tid] = iwg[tid];
    __syncthreads();

    // ---- phase 1: load image into padded interior ----
    for (int p = tid; p < 784; p += TPB) {
        int y = p / 28, xx = p - y * 28;
        spad[(y + 2) * 32 + (xx + 2)] = xg[(size_t)b * 784 + p];
    }
    __syncthreads();

    // ---- conv1 + relu: spad -> sh1 ----
    for (int c = 0; c < 8; ++c) {
        const float bias = sb1[c];
        float wr[25];
        #pragma unroll
        for (int k = 0; k < 25; ++k) wr[k] = sw1[c * 25 + k];
        for (int p = tid; p < 784; p += TPB) {
            int y = p / 28, xx = p - y * 28;
            const float* src = spad + y * 32 + xx;   // padded base: output (y,x) reads rows y..y+4
            float v = bias;
            #pragma unroll
            for (int ky = 0; ky < 5; ++ky)
                #pragma unroll
                for (int kx = 0; kx < 5; ++kx)
                    v = fmaf(src[ky * 32 + kx], wr[ky * 5 + kx], v);
            sh1[c * 1032 + (y + 2) * 32 + (xx + 2)] = fmaxf(v, 0.f);
        }
    }
    __syncthreads();

    // ---- conv2 + relu + maxpool3 (fused; only pooled positions computed) ----
    // Each thread owns pooled outputs o = s*16 + c. Register-caches a 7x7 input
    // patch per ic (covers the 3x3 pool window's 5x5 taps) + 25 weights.
    for (int o = tid; o < 1296; o += TPB) {
        const int c = o & 15, s = o >> 4;
        const int py = s / 9, px = s - py * 9;
        const int y0 = 3 * py, x0 = 3 * px;
        const float bias = sb2[c];
        float v[9];
        #pragma unroll
        for (int i = 0; i < 9; ++i) v[i] = bias;
        for (int ic = 0; ic < 8; ++ic) {
            float patch[49];
            const float* src = sh1 + ic * 1032 + y0 * 32 + x0;
            #pragma unroll
            for (int r = 0; r < 7; ++r)
                #pragma unroll
                for (int cc = 0; cc < 7; ++cc)
                    patch[r * 7 + cc] = src[r * 32 + cc];
            float wr[25];
            const float* wt = sw2t + ic * 25 * 16 + c;
            #pragma unroll
            for (int k = 0; k < 25; ++k) wr[k] = wt[k * 16];
            #pragma unroll
            for (int dy = 0; dy < 3; ++dy)
                #pragma unroll
                for (int dx = 0; dx < 3; ++dx)
                    #pragma unroll
                    for (int ky = 0; ky < 5; ++ky)
                        #pragma unroll
                        for (int kx = 0; kx < 5; ++kx)
                            v[dy * 3 + dx] = fmaf(patch[(dy + ky) * 7 + (dx + kx)],
                                                  wr[ky * 5 + kx], v[dy * 3 + dx]);
        }
        float m = 0.f;  // relu folded into max (all relu outputs >= 0)
        #pragma unroll
        for (int i = 0; i < 9; ++i) m = fmaxf(m, v[i]);
        pooled[c * 81 + s] = m;
    }
    __syncthreads();

    // ---- fc (1296 -> 10), wave-shuffle reduce, softmax ----
    float part[10];
    #pragma unroll
    for (int j = 0; j < 10; ++j) part[j] = 0.f;
    for (int i = tid; i < 1296; i += TPB) {
        const float pv = pooled[i];
        #pragma unroll
        for (int j = 0; j < 10; ++j)
            part[j] = fmaf(pv, fcwg[j * 1296 + i], part[j]);
    }
    {
        const int lane = tid & 63, wid = tid >> 6;
        #pragma unroll
        for (int j = 0; j < 10; ++j) {
            float v = part[j];
            #pragma unroll
            for (int off = 32; off > 0; off >>= 1) v += __shfl_down(v, off, 64);
            if (lane == 0) swred[wid * 10 + j] = v;
        }
    }
    __syncthreads();
    if (tid == 0) {
        float lg[10];
        float mx = -FLT_MAX;
        #pragma unroll
        for (int j = 0; j < 10; ++j) {
            lg[j] = swred[j] + swred[10 + j] + swred[20 + j] + swred[30 + j] + fcbg[j];
            mx = fmaxf(mx, lg[j]);
        }
        float sum = 0.f;
        #pragma unroll
        for (int j = 0; j < 10; ++j) { float e = expf(lg[j] - mx); sprobs[j] = e; sum += e; }
        const float inv = 1.f / sum;
        #pragma unroll
        for (int j = 0; j < 10; ++j) sprobs[j] *= inv;
    }
    __syncthreads();

    // ---- scan: y0=x, y_{n} = conv(y_{n-1}); out = sum_n probs[n]*y_n ----
    // Ping-pong buffers reuse sh1 channel-0/1 slices (borders still zero).
    float* bufA = sh1;
    float* bufB = sh1 + 1032;
    for (int p = tid; p < 784; p += TPB) {
        int y = p / 28, xx = p - y * 28;
        acc[p] = sprobs[0] * spad[(y + 2) * 32 + (xx + 2)];
    }
    float iw[25];
    #pragma unroll
    for (int k = 0; k < 25; ++k) iw[k] = siterw[k];
    const float* cur = spad;
    for (int n = 1; n < 10; ++n) {
        float* nxt = (n & 1) ? bufA : bufB;
        const float pn = sprobs[n];
        for (int p = tid; p < 784; p += TPB) {
            int y = p / 28, xx = p - y * 28;
            const float* src = cur + y * 32 + xx;
            float v = 0.f;
            #pragma unroll
            for (int ky = 0; ky < 5; ++ky)
                #pragma unroll
                for (int kx = 0; kx < 5; ++kx)
                    v = fmaf(src[ky * 32 + kx], iw[ky * 5 + kx], v);
            nxt[(y + 2) * 32 + (xx + 2)] = v;
            acc[p] = fmaf(pn, v, acc[p]);
        }
        cur = nxt;
        __syncthreads();
    }

    // ---- write out ----
    for (int p = tid; p < 784; p += TPB)
        outg[(size_t)b * 784 + p] = acc[p];
}

extern "C" void kernel_launch(void* const* d_in, const int* in_sizes, int n_in,
                              void* d_out, int out_size, void* d_ws, size_t ws_size,
                              hipStream_t stream) {
    const float* x   = (const float*)d_in[0];
    const float* w1  = (const float*)d_in[1];
    const float* b1  = (const float*)d_in[2];
    const float* w2  = (const float*)d_in[3];
    const float* b2  = (const float*)d_in[4];
    const float* fcw = (const float*)d_in[5];
    const float* fcb = (const float*)d_in[6];
    const float* iw  = (const float*)d_in[7];
    float* out = (float*)d_out;
    const int B = in_sizes[0] / 784;
    modeld_fused<<<B, TPB, 0, stream>>>(x, w1, b1, w2, b2, fcw, fcb, iw, out);
}

// Round 2
// 155.093 us; speedup vs baseline: 3.5175x; 3.5175x over previous
//
#include <hip/hip_runtime.h>
#include <hip/hip_bf16.h>
#include <math.h>
#include <float.h>

#define TPB 256

typedef __fp16 f16x8 __attribute__((ext_vector_type(8)));
typedef __fp16 f16x4 __attribute__((ext_vector_type(4)));
typedef float  f32x4 __attribute__((ext_vector_type(4)));
typedef float  f32x2 __attribute__((ext_vector_type(2)));

// LDS arena (bytes):
//   spad   f32[32][36]        @0      4608   input padded; scan seed
//   sh1T   f16[31][32][8]     @4608   15872  conv1 out, ch-innermost  -> after GEMM:
//     scanA f32[32][36] @4608, scanB f32[32][36] @9216  (9216 B total)
//   h2     f16[736][16]       @20480  23552  conv2 out (relu'd)
//     sw2  f32[3200]   @20480 (dead before first h2 write; barrier-protected)
//   pooled f32[1296]          @44032  5184
//   sw1p   f32[8][28]         @49216  896    w1, stride-28 padded (16B-aligned rows)
//   sb2    f32[16]            @50112
//   siterw f32[25]            @50176
//   sprobs f32[16]            @50304
//   swred  f32[40]            @50368
//   sb1    f32[8]             @50624
#define LDS_TOTAL 50656

__global__ __launch_bounds__(TPB, 3) void modeld_fused(
    const float* __restrict__ xg,
    const float* __restrict__ w1g,
    const float* __restrict__ b1g,
    const float* __restrict__ w2g,
    const float* __restrict__ b2g,
    const float* __restrict__ fcwg,
    const float* __restrict__ fcbg,
    const float* __restrict__ iwg,
    float* __restrict__ outg)
{
    __shared__ __align__(16) char lds[LDS_TOTAL];
    float*  spad   = (float*)(lds);
    __fp16* sh1T   = (__fp16*)(lds + 4608);
    float*  scanA  = (float*)(lds + 4608);
    float*  scanB  = (float*)(lds + 9216);
    __fp16* h2     = (__fp16*)(lds + 20480);
    float*  sw2    = (float*)(lds + 20480);
    float*  pooled = (float*)(lds + 44032);
    float*  sw1p   = (float*)(lds + 49216);
    float*  sb2    = (float*)(lds + 50112);
    float*  siterw = (float*)(lds + 50176);
    float*  sprobs = (float*)(lds + 50304);
    float*  swred  = (float*)(lds + 50368);
    float*  sb1    = (float*)(lds + 50624);

    const int tid  = threadIdx.x;
    const int b    = blockIdx.x;
    const int lane = tid & 63;
    const int g    = lane >> 4;    // mfma 16-lane group
    const int cl   = lane & 15;    // mfma row(A)=ch / col(B,D)=pos-in-tile
    const int wid  = tid >> 6;

    // ---------------- phase 0: zero + stage ----------------
    {
        f32x4 z = {0.f, 0.f, 0.f, 0.f};
        for (int i = tid; i < 288; i += TPB) ((f32x4*)spad)[i] = z;          // 1152 f32
        for (int i = tid; i < 992; i += TPB) ((f32x4*)sh1T)[i] = z;          // 15872 B
        for (int i = tid; i < 800; i += TPB) ((f32x4*)sw2)[i] = ((const f32x4*)w2g)[i];
        for (int i = tid; i < 200; i += TPB) { int c = i / 25, k = i - c * 25; sw1p[c*28 + k] = w1g[i]; }
        if (tid < 16) sb2[tid] = b2g[tid];
        if (tid < 8)  sb1[tid] = b1g[tid];
        if (tid < 25) siterw[tid] = iwg[tid];
    }
    __syncthreads();

    // thread geometry for image-space phases: 196 threads = 28 rows x 7 col-quads
    const int yy = tid / 7;        // image row 0..27
    const int q  = tid - yy * 7;   // col quad 0..6 (cols q*4 .. q*4+3)

    // ---------------- phase 1: load x into spad interior ----------------
    if (tid < 196) {
        f32x4 v = *((const f32x4*)(xg + (size_t)b * 784 + yy * 28 + q * 4));
        *((f32x4*)(spad + (yy + 2) * 36 + q * 4 + 4)) = v;
    }
    __syncthreads();

    // ---------------- phase 2: conv1 + relu -> sh1T (f16, ch-innermost) ----------------
    if (tid < 196) {
        float p[5][8];
        const float* sp = spad + yy * 36 + q * 4 + 2;
        #pragma unroll
        for (int r = 0; r < 5; ++r)
            #pragma unroll
            for (int c2 = 0; c2 < 4; ++c2) {
                f32x2 v = *((const f32x2*)(sp + r * 36 + c2 * 2));
                p[r][c2 * 2] = v[0]; p[r][c2 * 2 + 1] = v[1];
            }
        float o[4][8];
        #pragma unroll
        for (int c = 0; c < 8; ++c) {
            float wr[28];
            #pragma unroll
            for (int m = 0; m < 7; ++m) {
                f32x4 v = *((const f32x4*)(sw1p + c * 28 + m * 4));
                wr[m*4] = v[0]; wr[m*4+1] = v[1]; wr[m*4+2] = v[2]; wr[m*4+3] = v[3];
            }
            const float bias = sb1[c];
            #pragma unroll
            for (int px = 0; px < 4; ++px) {
                float a = bias;
                #pragma unroll
                for (int ky = 0; ky < 5; ++ky)
                    #pragma unroll
                    for (int kx = 0; kx < 5; ++kx)
                        a = fmaf(p[ky][px + kx], wr[ky * 5 + kx], a);
                o[px][c] = fmaxf(a, 0.f);
            }
        }
        #pragma unroll
        for (int px = 0; px < 4; ++px) {
            f16x8 hv;
            #pragma unroll
            for (int j = 0; j < 8; ++j) hv[j] = (__fp16)o[px][j];
            *((f16x8*)(sh1T + ((yy + 2) * 32 + q * 4 + px + 2) * 8)) = hv;
        }
    }
    __syncthreads();

    // ---------------- phase 3a: build A (weight) fragments from sw2 ----------------
    // K order: k = tap*8 + ic (tap-major, ic-minor), K padded 200->224, 7 slices of 32.
    // A[ch=cl][klocal = g*8 + j] = w2[ch][ic=j][tap = 4t+g]
    f16x8 afrag[7];
    #pragma unroll
    for (int t = 0; t < 7; ++t) {
        const int tap = 4 * t + g;
        #pragma unroll
        for (int j = 0; j < 8; ++j) {
            float w = (tap <= 24) ? sw2[cl * 200 + j * 25 + tap] : 0.f;
            afrag[t][j] = (__fp16)w;
        }
    }
    f32x4 bias2;
    #pragma unroll
    for (int r = 0; r < 4; ++r) bias2[r] = sb2[g * 4 + r];
    int toff[7];
    #pragma unroll
    for (int t = 0; t < 7; ++t) {
        int tap = 4 * t + g; if (tap > 24) tap = 24;
        const int ky = tap / 5, kx = tap - 5 * ky;
        toff[t] = (ky * 32 + kx) * 8;
    }
    __syncthreads();   // sw2 reads done before GEMM overwrites the region with h2

    // ---------------- phase 3b: conv2 as MFMA GEMM -> h2 (relu, f16) ----------------
    for (int tile = wid; tile < 46; tile += 4) {
        const int wpos = tile * 16 + cl;
        int pos = wpos > 728 ? 728 : wpos;
        const int y = pos / 27, x = pos - y * 27;
        const int base = (y * 32 + x) * 8;
        f32x4 acc = bias2;
        #pragma unroll
        for (int t = 0; t < 7; ++t) {
            f16x8 bfrag = *((const f16x8*)(sh1T + base + toff[t]));
            acc = __builtin_amdgcn_mfma_f32_16x16x32_f16(afrag[t], bfrag, acc, 0, 0, 0);
        }
        if (wpos <= 728) {
            f16x4 hv;
            #pragma unroll
            for (int r = 0; r < 4; ++r) hv[r] = (__fp16)fmaxf(acc[r], 0.f);
            *((f16x4*)(h2 + wpos * 16 + g * 4)) = hv;   // D: row=ch=g*4+r, col=pos
        }
    }
    __syncthreads();

    // ---------------- phase 4: maxpool 3x3/3 -> pooled (flat order c*81 + py*9 + px) ----------------
    for (int o = tid; o < 1296; o += TPB) {
        const int c = o & 15, s = o >> 4;
        const int py = s / 9, px = s - py * 9;
        float m = 0.f;
        #pragma unroll
        for (int dy = 0; dy < 3; ++dy)
            #pragma unroll
            for (int dx = 0; dx < 3; ++dx) {
                const int pos = (3 * py + dy) * 27 + 3 * px + dx;
                m = fmaxf(m, (float)h2[pos * 16 + c]);
            }
        pooled[c * 81 + s] = m;
    }
    // zero scan ping-pong buffers (overlay dead sh1T region)
    {
        f32x4 z = {0.f, 0.f, 0.f, 0.f};
        for (int i = tid; i < 576; i += TPB) ((f32x4*)scanA)[i] = z;  // 2304 f32 = A+B
    }
    __syncthreads();

    // ---------------- phase 5: fc + softmax ----------------
    {
        float part[10];
        #pragma unroll
        for (int j = 0; j < 10; ++j) part[j] = 0.f;
        for (int i = tid; i < 1296; i += TPB) {
            const float pv = pooled[i];
            #pragma unroll
            for (int j = 0; j < 10; ++j)
                part[j] = fmaf(pv, fcwg[j * 1296 + i], part[j]);
        }
        #pragma unroll
        for (int j = 0; j < 10; ++j) {
            float v = part[j];
            #pragma unroll
            for (int off = 32; off > 0; off >>= 1) v += __shfl_down(v, off, 64);
            if (lane == 0) swred[wid * 10 + j] = v;
        }
    }
    __syncthreads();
    if (tid == 0) {
        float lg[10]; float mx = -FLT_MAX;
        #pragma unroll
        for (int j = 0; j < 10; ++j) {
            lg[j] = swred[j] + swred[10 + j] + swred[20 + j] + swred[30 + j] + fcbg[j];
            mx = fmaxf(mx, lg[j]);
        }
        float sum = 0.f;
        #pragma unroll
        for (int j = 0; j < 10; ++j) { float e = expf(lg[j] - mx); sprobs[j] = e; sum += e; }
        const float inv = 1.f / sum;
        #pragma unroll
        for (int j = 0; j < 10; ++j) sprobs[j] *= inv;
    }
    __syncthreads();

    // ---------------- phase 6: 9-step conv scan + prob mix (acc in registers) ----------------
    float iw[25];
    #pragma unroll
    for (int k = 0; k < 25; ++k) iw[k] = siterw[k];
    float accv[4] = {0.f, 0.f, 0.f, 0.f};
    const float p0 = sprobs[0];
    const float* cur = spad;
    float* nxt = scanA;
    for (int n = 1; n <= 9; ++n) {
        if (tid < 196) {
            float p[5][8];
            const float* sp = cur + yy * 36 + q * 4 + 2;
            #pragma unroll
            for (int r = 0; r < 5; ++r)
                #pragma unroll
                for (int c2 = 0; c2 < 4; ++c2) {
                    f32x2 v = *((const f32x2*)(sp + r * 36 + c2 * 2));
                    p[r][c2 * 2] = v[0]; p[r][c2 * 2 + 1] = v[1];
                }
            if (n == 1) {
                #pragma unroll
                for (int i = 0; i < 4; ++i) accv[i] = p0 * p[2][i + 2];
            }
            const float pn = sprobs[n];
            float v0[4];
            #pragma unroll
            for (int px = 0; px < 4; ++px) {
                float a = 0.f;
                #pragma unroll
                for (int ky = 0; ky < 5; ++ky)
                    #pragma unroll
                    for (int kx = 0; kx < 5; ++kx)
                        a = fmaf(p[ky][px + kx], iw[ky * 5 + kx], a);
                v0[px] = a;
            }
            f32x4 ov = {v0[0], v0[1], v0[2], v0[3]};
            *((f32x4*)(nxt + (yy + 2) * 36 + q * 4 + 4)) = ov;
            #pragma unroll
            for (int px = 0; px < 4; ++px) accv[px] = fmaf(pn, v0[px], accv[px]);
        }
        __syncthreads();
        cur = nxt;
        nxt = (n & 1) ? scanB : scanA;
    }
    if (tid < 196) {
        f32x4 ov = {accv[0], accv[1], accv[2], accv[3]};
        *((f32x4*)(outg + (size_t)b * 784 + yy * 28 + q * 4)) = ov;
    }
}

extern "C" void kernel_launch(void* const* d_in, const int* in_sizes, int n_in,
                              void* d_out, int out_size, void* d_ws, size_t ws_size,
                              hipStream_t stream) {
    const float* x   = (const float*)d_in[0];
    const float* w1  = (const float*)d_in[1];
    const float* b1  = (const float*)d_in[2];
    const float* w2  = (const float*)d_in[3];
    const float* b2  = (const float*)d_in[4];
    const float* fcw = (const float*)d_in[5];
    const float* fcb = (const float*)d_in[6];
    const float* iw  = (const float*)d_in[7];
    float* out = (float*)d_out;
    const int B = in_sizes[0] / 784;
    modeld_fused<<<B, TPB, 0, stream>>>(x, w1, b1, w2, b2, fcw, fcb, iw, out);
}